// Round 20
// baseline (701.411 us; speedup 1.0000x reference)
//
#include <hip/hip_runtime.h>
#include <math.h>

#define BT 2
#define SL 2048
#define HIDN 2048
#define NHEADS 16
#define DNOPE 128
#define DROPE 64
#define DVAL 128
#define QHEAD 192
#define QLRANK 1536
#define KVLRANK 512
#define TTOK (BT * SL)
// fused down-proj output layout: [qdown 1536 | ckv 576 | pad 64 | gate 2048]
#define FN 4224
#define FC_CKV 1536
#define FC_ROPE 2048
#define FC_GATE 2176
#define LOG2_10K 13.287712379549449f

typedef unsigned short u16;
typedef u16 u16x4 __attribute__((ext_vector_type(4)));
typedef u16 u16x8 __attribute__((ext_vector_type(8)));
typedef short bf16x8 __attribute__((ext_vector_type(8)));
typedef float f32x4 __attribute__((ext_vector_type(4)));

__device__ __forceinline__ u16 f2b(float f) {
    union { float f; unsigned u; } v; v.f = f;
    unsigned r = v.u + 0x7FFFu + ((v.u >> 16) & 1u);
    return (u16)(r >> 16);
}
__device__ __forceinline__ float b2f(u16 h) {
    union { unsigned u; float f; } v; v.u = ((unsigned)h) << 16;
    return v.f;
}
__device__ __forceinline__ float fexp2(float x) {  // 2^x via v_exp_f32
    float r;
    asm("v_exp_f32 %0, %1" : "=v"(r) : "v"(x));
    return r;
}

// async global->LDS, 16B per lane. dest = wave-uniform base; HW adds lane*16.
__device__ __forceinline__ void gl2lds16(const u16* g, u16* l) {
    __builtin_amdgcn_global_load_lds((const __attribute__((address_space(1))) unsigned int*)g,
                                     (__attribute__((address_space(3))) unsigned int*)l, 16, 0, 0);
}

// ---------------- fused precast: 6 weight transpose-casts + hs cast ----------------
__device__ __forceinline__ void tcast_tile(const float* __restrict__ in, u16* __restrict__ out,
                                           int R, int C, int tx, int ty, int t) {
    __shared__ u16 tile[64][72];
    const int c0 = tx * 64, r0 = ty * 64;
    const int tr = t >> 4, tc4 = (t & 15) * 4;
#pragma unroll
    for (int i = 0; i < 4; ++i) {
        const int r = tr + i * 16;
        const float4 v = *(const float4*)&in[(size_t)(r0 + r) * C + c0 + tc4];
        u16x4 u;
        u.x = f2b(v.x); u.y = f2b(v.y); u.z = f2b(v.z); u.w = f2b(v.w);
        *(u16x4*)&tile[r][tc4] = u;
    }
    __syncthreads();
#pragma unroll
    for (int i = 0; i < 4; ++i) {
        const int rr = tr + i * 16;  // output row = input col
        u16x4 u;
        u.x = tile[tc4 + 0][rr];
        u.y = tile[tc4 + 1][rr];
        u.z = tile[tc4 + 2][rr];
        u.w = tile[tc4 + 3][rr];
        *(u16x4*)&out[(size_t)(c0 + rr) * R + r0 + tc4] = u;
    }
}

__global__ __launch_bounds__(256) void precast_k(
    const float* __restrict__ Wq_down, const float* __restrict__ Wq_up,
    const float* __restrict__ Wkv_down, const float* __restrict__ Wkv_up,
    const float* __restrict__ W_gate, const float* __restrict__ W_out,
    const float* __restrict__ hs, u16* __restrict__ wqd_t, u16* __restrict__ wqu_t,
    u16* __restrict__ wkvd_t, u16* __restrict__ wkvu_t, u16* __restrict__ wg_t,
    u16* __restrict__ wo_t, u16* __restrict__ hs16) {
    const int tid = blockIdx.x;
    const int t = threadIdx.x;
    if (tid >= 4768) {  // hs f32 -> bf16
        int i = (tid - 4768) * 256 + t;
        for (; i < TTOK * HIDN / 4; i += 2048 * 256) {
            const float4 v = ((const float4*)hs)[i];
            u16x4 u;
            u.x = f2b(v.x); u.y = f2b(v.y); u.z = f2b(v.z); u.w = f2b(v.w);
            ((u16x4*)hs16)[i] = u;
        }
        return;
    }
    // seg tiles: wqd 24x32=768 | wqu 48x24=1152 | wkvd 9x32=288 | wkvu 64x8=512 | wg 1024 | wo 1024
    if (tid < 768) {
        tcast_tile(Wq_down, wqd_t, 2048, 1536, tid % 24, tid / 24, t);
    } else if (tid < 1920) {
        const int i = tid - 768;
        tcast_tile(Wq_up, wqu_t, 1536, 3072, i % 48, i / 48, t);
    } else if (tid < 2208) {
        const int i = tid - 1920;
        tcast_tile(Wkv_down, wkvd_t, 2048, 576, i % 9, i / 9, t);
    } else if (tid < 2720) {
        const int i = tid - 2208;
        tcast_tile(Wkv_up, wkvu_t, 512, 4096, i % 64, i / 64, t);
    } else if (tid < 3744) {
        const int i = tid - 2720;
        tcast_tile(W_gate, wg_t, 2048, 2048, i % 32, i / 32, t);
    } else {
        const int i = tid - 3744;
        tcast_tile(W_out, wo_t, 2048, 2048, i % 32, i / 32, t);
    }
}

// ---------------- bf16 MFMA GEMM: C[M,N] = A[M,K] @ Bt[N,K]^T ----------------
// 128x128 tile, BK=64, 256 threads (4 waves 2x2), 4x4 16x16x32 frags per wave.
// global_load_lds staging, linear LDS with XOR-swizzle; chunked XCD blockIdx swizzle.
// MODE: 1 f32 out; 2 bf16 + sigmoid for col>=FC_GATE.
template <int MODE>
__global__ __launch_bounds__(256) void gemm_bf16_k(const u16* __restrict__ A,
                                                   const u16* __restrict__ Bt,
                                                   void* __restrict__ Cv, int M, int N, int K) {
    __shared__ u16 As[128 * 64];
    __shared__ u16 Bs[128 * 64];
    const int t = threadIdx.x;
    const int nx = gridDim.x;
    const int bid = blockIdx.x + nx * blockIdx.y;
    const int cpx = (nx * gridDim.y) >> 3;
    const int swz = (bid & 7) * cpx + (bid >> 3);
    const int bn = (swz % nx) * 128, bm = (swz / nx) * 128;
    const int w = t >> 6, lane = t & 63;
    const int wr = (w >> 1) * 64, wc = (w & 1) * 64;
    const int lr = lane & 15, lg = lane >> 4;

    const int srow = w * 32 + (lane >> 3);
    const int scol = ((lane & 7) ^ ((lane >> 3) & 7)) * 8;
    const u16* Ag = A + (size_t)(bm + srow) * K + scol;
    const u16* Bg = Bt + (size_t)(bn + srow) * K + scol;
    u16* Asl = As + w * 2048;  // wave-uniform base (+ j*512)
    u16* Bsl = Bs + w * 2048;

    f32x4 acc[4][4];
#pragma unroll
    for (int i = 0; i < 4; ++i)
#pragma unroll
        for (int j = 0; j < 4; ++j) acc[i][j] = 0.f;

    for (int k0 = 0; k0 < K; k0 += 64) {
        __syncthreads();  // previous iteration's LDS reads done
#pragma unroll
        for (int j = 0; j < 4; ++j) gl2lds16(Ag + (size_t)(j * 8) * K + k0, Asl + j * 512);
#pragma unroll
        for (int j = 0; j < 4; ++j) gl2lds16(Bg + (size_t)(j * 8) * K + k0, Bsl + j * 512);
        __syncthreads();  // compiler drains vmcnt before barrier
#pragma unroll
        for (int kk = 0; kk < 2; ++kk) {
            bf16x8 af[4], bfr[4];
#pragma unroll
            for (int mi = 0; mi < 4; ++mi) {
                const int row = wr + mi * 16 + lr;
                const int idx = (row * 64 + kk * 32 + lg * 8) ^ ((row & 7) << 3);
                af[mi] = *(const bf16x8*)&As[idx];
            }
#pragma unroll
            for (int ni = 0; ni < 4; ++ni) {
                const int row = wc + ni * 16 + lr;
                const int idx = (row * 64 + kk * 32 + lg * 8) ^ ((row & 7) << 3);
                bfr[ni] = *(const bf16x8*)&Bs[idx];
            }
#pragma unroll
            for (int mi = 0; mi < 4; ++mi)
#pragma unroll
                for (int ni = 0; ni < 4; ++ni)
                    acc[mi][ni] = __builtin_amdgcn_mfma_f32_16x16x32_bf16(af[mi], bfr[ni],
                                                                          acc[mi][ni], 0, 0, 0);
        }
    }
#pragma unroll
    for (int mi = 0; mi < 4; ++mi)
#pragma unroll
        for (int ni = 0; ni < 4; ++ni) {
            const int row0 = bm + wr + mi * 16 + lg * 4;
            const int col = bn + wc + ni * 16 + lr;
#pragma unroll
            for (int r = 0; r < 4; ++r) {
                float v = acc[mi][ni][r];
                if (MODE == 2 && col >= FC_GATE) v = 1.f / (1.f + __expf(-v));
                if (MODE == 1)
                    ((float*)Cv)[(size_t)(row0 + r) * N + col] = v;
                else
                    ((u16*)Cv)[(size_t)(row0 + r) * N + col] = f2b(v);
            }
        }
}

// ---------------- merged up-projection GEMM (q-up + kv-up, one dispatch) ----------------
// blocks 0..767: q-tiles (24x32, own XCD swizzle cpx=96) with RoPE fused in epilogue;
// blocks 768..1791: kv-tiles (32x32, own XCD swizzle cpx=128), knope/vT split.
__global__ __launch_bounds__(256) void gemm_up_k(const u16* __restrict__ Aq,
                                                 const u16* __restrict__ Akv,
                                                 const u16* __restrict__ Btq,
                                                 const u16* __restrict__ Btkv,
                                                 const int* __restrict__ pos_ids,
                                                 u16* __restrict__ qbuf, u16* __restrict__ knope,
                                                 u16* __restrict__ vT) {
    __shared__ u16 As[128 * 64];
    __shared__ u16 Bs[128 * 64];
    const int t = threadIdx.x;
    const int bid = blockIdx.x;
    int tn, tm;
    bool isq;
    if (bid < 768) {  // q segment: identical mapping to standalone 24x32 dispatch
        isq = true;
        const int swz = (bid & 7) * 96 + (bid >> 3);
        tn = swz % 24;
        tm = swz / 24;
    } else {  // kv segment: identical mapping to standalone 32x32 dispatch
        isq = false;
        const int i = bid - 768;
        const int swz = (i & 7) * 128 + (i >> 3);
        tn = swz % 32;
        tm = swz / 32;
    }
    const int K = isq ? QLRANK : KVLRANK;
    const int bn = tn * 128, bm = tm * 128;
    const u16* A = isq ? Aq : Akv;
    const u16* Bt = isq ? Btq : Btkv;

    const int w = t >> 6, lane = t & 63;
    const int wr = (w >> 1) * 64, wc = (w & 1) * 64;
    const int lr = lane & 15, lg = lane >> 4;

    const int srow = w * 32 + (lane >> 3);
    const int scol = ((lane & 7) ^ ((lane >> 3) & 7)) * 8;
    const u16* Ag = A + (size_t)(bm + srow) * K + scol;
    const u16* Bg = Bt + (size_t)(bn + srow) * K + scol;
    u16* Asl = As + w * 2048;
    u16* Bsl = Bs + w * 2048;

    f32x4 acc[4][4];
#pragma unroll
    for (int i = 0; i < 4; ++i)
#pragma unroll
        for (int j = 0; j < 4; ++j) acc[i][j] = 0.f;

    for (int k0 = 0; k0 < K; k0 += 64) {
        __syncthreads();
#pragma unroll
        for (int j = 0; j < 4; ++j) gl2lds16(Ag + (size_t)(j * 8) * K + k0, Asl + j * 512);
#pragma unroll
        for (int j = 0; j < 4; ++j) gl2lds16(Bg + (size_t)(j * 8) * K + k0, Bsl + j * 512);
        __syncthreads();
#pragma unroll
        for (int kk = 0; kk < 2; ++kk) {
            bf16x8 af[4], bfr[4];
#pragma unroll
            for (int mi = 0; mi < 4; ++mi) {
                const int row = wr + mi * 16 + lr;
                const int idx = (row * 64 + kk * 32 + lg * 8) ^ ((row & 7) << 3);
                af[mi] = *(const bf16x8*)&As[idx];
            }
#pragma unroll
            for (int ni = 0; ni < 4; ++ni) {
                const int row = wc + ni * 16 + lr;
                const int idx = (row * 64 + kk * 32 + lg * 8) ^ ((row & 7) << 3);
                bfr[ni] = *(const bf16x8*)&Bs[idx];
            }
#pragma unroll
            for (int mi = 0; mi < 4; ++mi)
#pragma unroll
                for (int ni = 0; ni < 4; ++ni)
                    acc[mi][ni] = __builtin_amdgcn_mfma_f32_16x16x32_bf16(af[mi], bfr[ni],
                                                                          acc[mi][ni], 0, 0, 0);
        }
    }
#pragma unroll
    for (int mi = 0; mi < 4; ++mi)
#pragma unroll
        for (int ni = 0; ni < 4; ++ni) {
            const int row0 = bm + wr + mi * 16 + lg * 4;
            const int col = bn + wc + ni * 16 + lr;
            if (isq) {
                // head-relative col; each 16-col frag is wholly nope or wholly rope
                // (192 % 16 == 0), so the branch is wave-uniform -> shfl is safe.
                const int h = col / 192;
                const int hcol = col - h * 192;
                if (hcol < DNOPE) {
#pragma unroll
                    for (int r = 0; r < 4; ++r)
                        qbuf[(size_t)(row0 + r) * (NHEADS * QHEAD) + col] = f2b(acc[mi][ni][r]);
                } else {
                    // RoPE fused: pair (2j,2j+1) sits in adjacent lanes.
                    const int j2 = hcol - DNOPE;
                    const int j = j2 >> 1;
                    const bool odd = j2 & 1;
                    const float inv = fexp2(-(float)(2 * j) * (LOG2_10K / 64.f));
                    const int colo = h * 192 + DNOPE + j + (odd ? 32 : 0);
#pragma unroll
                    for (int r = 0; r < 4; ++r) {
                        const float mine = acc[mi][ni][r];
                        const float part = __shfl_xor(mine, 1);
                        const float pos = (float)pos_ids[(row0 + r) & (SL - 1)];
                        const float f = pos * inv;
                        const float c = cosf(f), sn = sinf(f);
                        const float v = odd ? (mine * c + part * sn) : (mine * c - part * sn);
                        qbuf[(size_t)(row0 + r) * (NHEADS * QHEAD) + colo] = f2b(v);
                    }
                }
            } else {
                const int h = col >> 8, cd = col & 255;
                if (cd < 128) {
#pragma unroll
                    for (int r = 0; r < 4; ++r)
                        knope[(size_t)(row0 + r) * 2048 + h * 128 + cd] = f2b(acc[mi][ni][r]);
                } else {
                    u16x4 pk;
                    pk.x = f2b(acc[mi][ni][0]);
                    pk.y = f2b(acc[mi][ni][1]);
                    pk.z = f2b(acc[mi][ni][2]);
                    pk.w = f2b(acc[mi][ni][3]);
                    const int bb = row0 >> 11;
                    *(u16x4*)&vT[((size_t)((bb * 16 + h) * 128 + (cd - 128))) * SL +
                                 (row0 & (SL - 1))] = pk;
                }
            }
        }
}

// ---------------- fused RMS norms + k-RoPE ----------------
// blocks [0, 2T): rms norms (q / kv). blocks [2T, 2T+512): kr from fout rope slice.
__global__ __launch_bounds__(256) void rms2_k(const u16* __restrict__ fout,
                                              const float* __restrict__ qw,
                                              const float* __restrict__ kw,
                                              const int* __restrict__ pos_ids,
                                              u16* __restrict__ qn, u16* __restrict__ kvn,
                                              u16* __restrict__ kr) {
    const int rid = blockIdx.x;
    const int t = threadIdx.x;
    if (rid >= 2 * TTOK) {  // k-RoPE: 8 tokens/block, 32 lanes/token
        const int tok = (rid - 2 * TTOK) * 8 + (t >> 5);
        const int j = t & 31;
        const int s = tok & (SL - 1);
        const float pos = (float)pos_ids[s];
        const float inv = fexp2(-(float)(2 * j) * (LOG2_10K / 64.f));
        const float f = pos * inv;
        const float c = cosf(f), sn = sinf(f);
        const u16* kc = fout + (size_t)tok * FN + FC_ROPE;
        const unsigned kp = *(const unsigned*)&kc[2 * j];
        const float ke = b2f((u16)(kp & 0xffff)), ko = b2f((u16)(kp >> 16));
        kr[tok * 64 + j] = f2b(ke * c - ko * sn);
        kr[tok * 64 + 32 + j] = f2b(ko * c + ke * sn);
        return;
    }
    const bool isq = rid < TTOK;
    const int row = isq ? rid : rid - TTOK;
    const int n = isq ? QLRANK : KVLRANK;
    const u16* x = fout + (size_t)row * FN + (isq ? 0 : FC_CKV);
    const float* w = isq ? qw : kw;
    u16* y = isq ? (qn + (size_t)row * QLRANK) : (kvn + (size_t)row * KVLRANK);
    float ss = 0.f;
    for (int d = t * 4; d < n; d += 1024) {
        const u16x4 u = *(const u16x4*)&x[d];
        const float a = b2f(u.x), b = b2f(u.y), c = b2f(u.z), e = b2f(u.w);
        ss += a * a + b * b + c * c + e * e;
    }
    ss += __shfl_down(ss, 32);
    ss += __shfl_down(ss, 16);
    ss += __shfl_down(ss, 8);
    ss += __shfl_down(ss, 4);
    ss += __shfl_down(ss, 2);
    ss += __shfl_down(ss, 1);
    __shared__ float red[5];
    if ((t & 63) == 0) red[t >> 6] = ss;
    __syncthreads();
    if (t == 0) red[4] = rsqrtf((red[0] + red[1] + red[2] + red[3]) / (float)n + 1e-6f);
    __syncthreads();
    const float sc = red[4];
    for (int d = t * 4; d < n; d += 1024) {
        const u16x4 u = *(const u16x4*)&x[d];
        const float4 wv = *(const float4*)&w[d];
        u16x4 o;
        o.x = f2b(b2f(u.x) * sc * (1.f + wv.x));
        o.y = f2b(b2f(u.y) * sc * (1.f + wv.y));
        o.z = f2b(b2f(u.z) * sc * (1.f + wv.z));
        o.w = f2b(b2f(u.w) * sc * (1.f + wv.w));
        *(u16x4*)&y[d] = o;
    }
}

// ---------------- MFMA flash attention, gate fused ----------------
// block = 256 (4 waves); q-tile 128 (32 rows/wave via 2 m-frags); key tiles of 64.
// grid (bh, qt): all q-tiles of one (b,h) share an XCD -> K/V L2 reuse by placement.
// reg-prefetch of next K/V tile hides L2 latency under compute.
// Q pre-scaled by scale*log2e; softmax in exp2 domain (v_exp_f32 direct).
// Row-sum l computed via MFMA-with-ones; defer-max gate via one 6-shuffle wave max.
#define PSTR 76
__global__ __launch_bounds__(256, 2) void mla_attn_k(const u16* __restrict__ qbuf,
                                                     const u16* __restrict__ knope,
                                                     const u16* __restrict__ kr,
                                                     const u16* __restrict__ vT,
                                                     const u16* __restrict__ gateb,
                                                     u16* __restrict__ outg) {
    __shared__ u16 Ks[64 * 200];
    __shared__ u16 Vt[128 * 72];
    __shared__ u16 Ps[4 * 32 * PSTR];
    const int bh = blockIdx.x;
    const int b = bh >> 4, h = bh & 15;
    const int q0 = blockIdx.y * 128;
    const int t = threadIdx.x, w = t >> 6, lane = t & 63;
    const int lr = lane & 15, lg = lane >> 4;
    const float qs = 0.07216878364870322f * 1.4426950408889634f;
    const float THR = 8.f * 1.4426950408889634f;

    int kRow[6], kC8[6];
#pragma unroll
    for (int c = 0; c < 6; ++c) {
        const int i = t + c * 256;
        kRow[c] = i / 24;
        kC8[c] = (i % 24) * 8;
    }
    int vRow[4], vC8[4];
#pragma unroll
    for (int c = 0; c < 4; ++c) {
        const int i = t + c * 256;
        vRow[c] = i >> 3;
        vC8[c] = (i & 7) * 8;
    }

    bf16x8 aq[2][6];
#pragma unroll
    for (int mi = 0; mi < 2; ++mi) {
        const int qrow = b * SL + q0 + w * 32 + mi * 16 + lr;
#pragma unroll
        for (int ks = 0; ks < 6; ++ks) {
            const u16x8 raw = *(const u16x8*)&qbuf[(size_t)qrow * (NHEADS * QHEAD) + h * QHEAD +
                                                   ks * 32 + lg * 8];
            bf16x8 o;
#pragma unroll
            for (int j = 0; j < 8; ++j) o[j] = (short)f2b(b2f(raw[j]) * qs);
            aq[mi][ks] = o;
        }
    }
    bf16x8 ones;
#pragma unroll
    for (int j = 0; j < 8; ++j) ones[j] = (short)0x3F80;

    f32x4 O[2][8];
#pragma unroll
    for (int mi = 0; mi < 2; ++mi)
#pragma unroll
        for (int df = 0; df < 8; ++df) O[mi][df] = 0.f;
    f32x4 Ol[2];
    Ol[0] = 0.f;
    Ol[1] = 0.f;
    float m[2][4];
#pragma unroll
    for (int mi = 0; mi < 2; ++mi)
#pragma unroll
        for (int r = 0; r < 4; ++r) m[mi][r] = -INFINITY;

    u16x8 kreg[6], vreg[4];
#define ATTN_ISSUE_K(K0)                                                                     \
    {                                                                                        \
        _Pragma("unroll") for (int c = 0; c < 6; ++c) {                                      \
            const int tok = b * SL + (K0) + kRow[c];                                         \
            kreg[c] = (kC8[c] < 128)                                                         \
                          ? *(const u16x8*)&knope[(size_t)tok * 2048 + h * 128 + kC8[c]]     \
                          : *(const u16x8*)&kr[(size_t)tok * 64 + (kC8[c] - 128)];           \
        }                                                                                    \
    }
#define ATTN_ISSUE_V(K0)                                                                     \
    {                                                                                        \
        _Pragma("unroll") for (int c = 0; c < 4; ++c)                                        \
            vreg[c] = *(const u16x8*)&vT[(size_t)(bh * 128 + vRow[c]) * SL + (K0) + vC8[c]]; \
    }

    ATTN_ISSUE_K(0);
    ATTN_ISSUE_V(0);

    for (int it = 0; it < SL / 64; ++it) {
        __syncthreads();
#pragma unroll
        for (int c = 0; c < 6; ++c) *(u16x8*)&Ks[kRow[c] * 200 + kC8[c]] = kreg[c];
#pragma unroll
        for (int c = 0; c < 4; ++c) *(u16x8*)&Vt[vRow[c] * 72 + vC8[c]] = vreg[c];
        __syncthreads();
        const bool more = (it + 1) < SL / 64;
        const int kn = (it + 1) * 64;
        if (more) ATTN_ISSUE_K(kn);

        f32x4 s[2][4];
#pragma unroll
        for (int mi = 0; mi < 2; ++mi)
#pragma unroll
            for (int nf = 0; nf < 4; ++nf) s[mi][nf] = 0.f;
#pragma unroll
        for (int ks = 0; ks < 6; ++ks) {
#pragma unroll
            for (int nf = 0; nf < 4; ++nf) {
                const bf16x8 bk = *(const bf16x8*)&Ks[(nf * 16 + lr) * 200 + ks * 32 + lg * 8];
                s[0][nf] = __builtin_amdgcn_mfma_f32_16x16x32_bf16(aq[0][ks], bk, s[0][nf], 0, 0, 0);
                s[1][nf] = __builtin_amdgcn_mfma_f32_16x16x32_bf16(aq[1][ks], bk, s[1][nf], 0, 0, 0);
            }
        }

        float g = -INFINITY;
#pragma unroll
        for (int mi = 0; mi < 2; ++mi)
#pragma unroll
            for (int r = 0; r < 4; ++r) {
                const float lmax =
                    fmaxf(fmaxf(s[mi][0][r], s[mi][1][r]), fmaxf(s[mi][2][r], s[mi][3][r]));
                g = fmaxf(g, lmax - m[mi][r]);
            }
        g = fmaxf(g, __shfl_xor(g, 1));
        g = fmaxf(g, __shfl_xor(g, 2));
        g = fmaxf(g, __shfl_xor(g, 4));
        g = fmaxf(g, __shfl_xor(g, 8));
        g = fmaxf(g, __shfl_xor(g, 16));
        g = fmaxf(g, __shfl_xor(g, 32));
        if (!(g <= THR)) {
#pragma unroll
            for (int mi = 0; mi < 2; ++mi)
#pragma unroll
                for (int r = 0; r < 4; ++r) {
                    float lm =
                        fmaxf(fmaxf(s[mi][0][r], s[mi][1][r]), fmaxf(s[mi][2][r], s[mi][3][r]));
                    lm = fmaxf(lm, __shfl_xor(lm, 1));
                    lm = fmaxf(lm, __shfl_xor(lm, 2));
                    lm = fmaxf(lm, __shfl_xor(lm, 4));
                    lm = fmaxf(lm, __shfl_xor(lm, 8));
                    const float mn = fmaxf(m[mi][r], lm);
                    const float al = fexp2(m[mi][r] - mn);
                    m[mi][r] = mn;
                    Ol[mi][r] *= al;
#pragma unroll
                    for (int df = 0; df < 8; ++df) O[mi][df][r] *= al;
                }
        }

#pragma unroll
        for (int mi = 0; mi < 2; ++mi) {
            const int pb = w * 32 * PSTR + mi * 16 * PSTR;
#pragma unroll
            for (int r = 0; r < 4; ++r) {
                const float mn = m[mi][r];
                const int prow = pb + (lg * 4 + r) * PSTR + lr;
                Ps[prow] = f2b(fexp2(s[mi][0][r] - mn));
                Ps[prow + 16] = f2b(fexp2(s[mi][1][r] - mn));
                Ps[prow + 32] = f2b(fexp2(s[mi][2][r] - mn));
                Ps[prow + 48] = f2b(fexp2(s[mi][3][r] - mn));
            }
        }

        if (more) ATTN_ISSUE_V(kn);

        bf16x8 pa[2][2];
#pragma unroll
        for (int mi = 0; mi < 2; ++mi)
#pragma unroll
            for (int ks2 = 0; ks2 < 2; ++ks2)
                pa[mi][ks2] =
                    *(const bf16x8*)&Ps[w * 32 * PSTR + (mi * 16 + lr) * PSTR + ks2 * 32 + lg * 8];
#pragma unroll
        for (int mi = 0; mi < 2; ++mi)
#pragma unroll
            for (int ks2 = 0; ks2 < 2; ++ks2)
                Ol[mi] = __builtin_amdgcn_mfma_f32_16x16x32_bf16(pa[mi][ks2], ones, Ol[mi], 0, 0, 0);
#pragma unroll
        for (int df = 0; df < 8; ++df)
#pragma unroll
            for (int ks2 = 0; ks2 < 2; ++ks2) {
                const bf16x8 bv = *(const bf16x8*)&Vt[(df * 16 + lr) * 72 + ks2 * 32 + lg * 8];
                O[0][df] = __builtin_amdgcn_mfma_f32_16x16x32_bf16(pa[0][ks2], bv, O[0][df], 0, 0, 0);
                O[1][df] = __builtin_amdgcn_mfma_f32_16x16x32_bf16(pa[1][ks2], bv, O[1][df], 0, 0, 0);
            }
    }
#pragma unroll
    for (int mi = 0; mi < 2; ++mi) {
        float invl[4];
#pragma unroll
        for (int r = 0; r < 4; ++r) invl[r] = 1.f / Ol[mi][r];
#pragma unroll
        for (int df = 0; df < 8; ++df)
#pragma unroll
            for (int r = 0; r < 4; ++r) {
                const int qq = b * SL + q0 + w * 32 + mi * 16 + lg * 4 + r;
                const int col = h * DVAL + df * 16 + lr;
                const float o = O[mi][df][r] * invl[r];
                const float gg = b2f(gateb[(size_t)qq * FN + col]);
                outg[(size_t)qq * (NHEADS * DVAL) + col] = f2b(o * gg);
            }
    }
}

extern "C" void kernel_launch(void* const* d_in, const int* in_sizes, int n_in, void* d_out,
                              int out_size, void* d_ws, size_t ws_size, hipStream_t stream) {
    const float* hs = (const float*)d_in[0];
    const int* pos = (const int*)d_in[1];
    const float* Wq_down = (const float*)d_in[2];
    const float* q_norm_w = (const float*)d_in[3];
    const float* Wq_up = (const float*)d_in[4];
    const float* Wkv_down = (const float*)d_in[5];
    const float* kv_norm_w = (const float*)d_in[6];
    const float* Wkv_up = (const float*)d_in[7];
    const float* W_gate = (const float*)d_in[8];
    const float* W_out = (const float*)d_in[9];
    float* out = (float*)d_out;

    u16* p = (u16*)d_ws;
    u16* hs16 = p;      p += (size_t)TTOK * HIDN;
    u16* wdown_t = p;   p += (size_t)FN * HIDN;
    u16* wqd_t = wdown_t;
    u16* wkvd_t = wdown_t + (size_t)QLRANK * HIDN;
    u16* wg_t = wdown_t + (size_t)FC_GATE * HIDN;
    u16* wqu_t = p;     p += (size_t)(NHEADS * QHEAD) * QLRANK;
    u16* wkvu_t = p;    p += (size_t)(NHEADS * 256) * KVLRANK;
    u16* wo_t = p;      p += (size_t)HIDN * (NHEADS * DVAL);
    u16* fout = p;      p += (size_t)TTOK * FN;
    u16* qdownN = p;    p += (size_t)TTOK * QLRANK;
    u16* qbuf = p;      p += (size_t)TTOK * (NHEADS * QHEAD);
    u16* kvn = p;       p += (size_t)TTOK * KVLRANK;
    u16* knope = p;     p += (size_t)TTOK * (NHEADS * DNOPE);
    u16* krb = p;       p += (size_t)TTOK * DROPE;
    u16* vTg = p;       p += (size_t)32 * 128 * SL;
    u16* outg = p;      p += (size_t)TTOK * (NHEADS * DVAL);

    const dim3 blk(256);

    precast_k<<<dim3(6816), blk, 0, stream>>>(Wq_down, Wq_up, Wkv_down, Wkv_up, W_gate, W_out, hs,
                                              wqd_t, wqu_t, wkvd_t, wkvu_t, wg_t, wo_t, hs16);

    gemm_bf16_k<2><<<dim3(FN / 128, TTOK / 128), blk, 0, stream>>>(hs16, wdown_t, fout, TTOK, FN,
                                                                   HIDN);
    // rms norms + k-RoPE in one launch
    rms2_k<<<dim3(2 * TTOK + TTOK / 8), blk, 0, stream>>>(fout, q_norm_w, kv_norm_w, pos, qdownN,
                                                          kvn, krb);
    // merged q-up (RoPE fused) + kv-up (knope/vT split), per-segment XCD swizzle
    gemm_up_k<<<dim3(1792), blk, 0, stream>>>(qdownN, kvn, wqu_t, wkvu_t, pos, qbuf, knope, vTg);

    mla_attn_k<<<dim3(32, SL / 128), blk, 0, stream>>>(qbuf, knope, krb, vTg, fout + FC_GATE, outg);

    gemm_bf16_k<1><<<dim3(HIDN / 128, TTOK / 128), blk, 0, stream>>>(outg, wo_t, out, TTOK, HIDN,
                                                                     NHEADS * DVAL);
}

// Round 21
// 431.097 us; speedup vs baseline: 1.6270x; 1.6270x over previous
//
#include <hip/hip_runtime.h>
#include <math.h>

#define BT 2
#define SL 2048
#define HIDN 2048
#define NHEADS 16
#define DNOPE 128
#define DROPE 64
#define DVAL 128
#define QHEAD 192
#define QLRANK 1536
#define KVLRANK 512
#define TTOK (BT * SL)
// fused down-proj output layout: [qdown 1536 | ckv 576 | pad 64 | gate 2048]
#define FN 4224
#define FC_CKV 1536
#define FC_ROPE 2048
#define FC_GATE 2176

typedef unsigned short u16;
typedef u16 u16x4 __attribute__((ext_vector_type(4)));
typedef u16 u16x8 __attribute__((ext_vector_type(8)));
typedef short bf16x8 __attribute__((ext_vector_type(8)));
typedef float f32x4 __attribute__((ext_vector_type(4)));

__device__ __forceinline__ u16 f2b(float f) {
    union { float f; unsigned u; } v; v.f = f;
    unsigned r = v.u + 0x7FFFu + ((v.u >> 16) & 1u);
    return (u16)(r >> 16);
}
__device__ __forceinline__ float b2f(u16 h) {
    union { unsigned u; float f; } v; v.u = ((unsigned)h) << 16;
    return v.f;
}
__device__ __forceinline__ float fexp2(float x) {  // 2^x via v_exp_f32
    float r;
    asm("v_exp_f32 %0, %1" : "=v"(r) : "v"(x));
    return r;
}

// async global->LDS, 16B per lane. dest = wave-uniform base; HW adds lane*16.
__device__ __forceinline__ void gl2lds16(const u16* g, u16* l) {
    __builtin_amdgcn_global_load_lds((const __attribute__((address_space(1))) unsigned int*)g,
                                     (__attribute__((address_space(3))) unsigned int*)l, 16, 0, 0);
}

// ---------------- fused precast: 6 weight transpose-casts + hs cast ----------------
__device__ __forceinline__ void tcast_tile(const float* __restrict__ in, u16* __restrict__ out,
                                           int R, int C, int tx, int ty, int t) {
    __shared__ u16 tile[64][72];
    const int c0 = tx * 64, r0 = ty * 64;
    const int tr = t >> 4, tc4 = (t & 15) * 4;
#pragma unroll
    for (int i = 0; i < 4; ++i) {
        const int r = tr + i * 16;
        const float4 v = *(const float4*)&in[(size_t)(r0 + r) * C + c0 + tc4];
        u16x4 u;
        u.x = f2b(v.x); u.y = f2b(v.y); u.z = f2b(v.z); u.w = f2b(v.w);
        *(u16x4*)&tile[r][tc4] = u;
    }
    __syncthreads();
#pragma unroll
    for (int i = 0; i < 4; ++i) {
        const int rr = tr + i * 16;  // output row = input col
        u16x4 u;
        u.x = tile[tc4 + 0][rr];
        u.y = tile[tc4 + 1][rr];
        u.z = tile[tc4 + 2][rr];
        u.w = tile[tc4 + 3][rr];
        *(u16x4*)&out[(size_t)(c0 + rr) * R + r0 + tc4] = u;
    }
}

__global__ __launch_bounds__(256) void precast_k(
    const float* __restrict__ Wq_down, const float* __restrict__ Wq_up,
    const float* __restrict__ Wkv_down, const float* __restrict__ Wkv_up,
    const float* __restrict__ W_gate, const float* __restrict__ W_out,
    const float* __restrict__ hs, u16* __restrict__ wqd_t, u16* __restrict__ wqu_t,
    u16* __restrict__ wkvd_t, u16* __restrict__ wkvu_t, u16* __restrict__ wg_t,
    u16* __restrict__ wo_t, u16* __restrict__ hs16) {
    const int tid = blockIdx.x;
    const int t = threadIdx.x;
    if (tid >= 4768) {  // hs f32 -> bf16
        int i = (tid - 4768) * 256 + t;
        for (; i < TTOK * HIDN / 4; i += 2048 * 256) {
            const float4 v = ((const float4*)hs)[i];
            u16x4 u;
            u.x = f2b(v.x); u.y = f2b(v.y); u.z = f2b(v.z); u.w = f2b(v.w);
            ((u16x4*)hs16)[i] = u;
        }
        return;
    }
    // seg tiles: wqd 24x32=768 | wqu 48x24=1152 | wkvd 9x32=288 | wkvu 64x8=512 | wg 1024 | wo 1024
    if (tid < 768) {
        tcast_tile(Wq_down, wqd_t, 2048, 1536, tid % 24, tid / 24, t);
    } else if (tid < 1920) {
        const int i = tid - 768;
        tcast_tile(Wq_up, wqu_t, 1536, 3072, i % 48, i / 48, t);
    } else if (tid < 2208) {
        const int i = tid - 1920;
        tcast_tile(Wkv_down, wkvd_t, 2048, 576, i % 9, i / 9, t);
    } else if (tid < 2720) {
        const int i = tid - 2208;
        tcast_tile(Wkv_up, wkvu_t, 512, 4096, i % 64, i / 64, t);
    } else if (tid < 3744) {
        const int i = tid - 2720;
        tcast_tile(W_gate, wg_t, 2048, 2048, i % 32, i / 32, t);
    } else {
        const int i = tid - 3744;
        tcast_tile(W_out, wo_t, 2048, 2048, i % 32, i / 32, t);
    }
}

// ---------------- bf16 MFMA GEMM: C[M,N] = A[M,K] @ Bt[N,K]^T ----------------
// 128x128 tile, BK=64, 256 threads (4 waves 2x2), 4x4 16x16x32 frags per wave.
// global_load_lds staging, linear LDS with XOR-swizzle; chunked XCD blockIdx swizzle.
// MODE: 1 f32 out; 2 bf16 + sigmoid for col>=FC_GATE.
template <int MODE>
__global__ __launch_bounds__(256) void gemm_bf16_k(const u16* __restrict__ A,
                                                   const u16* __restrict__ Bt,
                                                   void* __restrict__ Cv, int M, int N, int K) {
    __shared__ u16 As[128 * 64];
    __shared__ u16 Bs[128 * 64];
    const int t = threadIdx.x;
    // chunked XCD swizzle (nwg % 8 == 0 for all our launches)
    const int nx = gridDim.x;
    const int bid = blockIdx.x + nx * blockIdx.y;
    const int cpx = (nx * gridDim.y) >> 3;
    const int swz = (bid & 7) * cpx + (bid >> 3);
    const int bn = (swz % nx) * 128, bm = (swz / nx) * 128;
    const int w = t >> 6, lane = t & 63;
    const int wr = (w >> 1) * 64, wc = (w & 1) * 64;
    const int lr = lane & 15, lg = lane >> 4;

    const int srow = w * 32 + (lane >> 3);
    const int scol = ((lane & 7) ^ ((lane >> 3) & 7)) * 8;
    const u16* Ag = A + (size_t)(bm + srow) * K + scol;
    const u16* Bg = Bt + (size_t)(bn + srow) * K + scol;
    u16* Asl = As + w * 2048;  // wave-uniform base (+ j*512)
    u16* Bsl = Bs + w * 2048;

    f32x4 acc[4][4];
#pragma unroll
    for (int i = 0; i < 4; ++i)
#pragma unroll
        for (int j = 0; j < 4; ++j) acc[i][j] = 0.f;

    for (int k0 = 0; k0 < K; k0 += 64) {
        __syncthreads();  // previous iteration's LDS reads done
#pragma unroll
        for (int j = 0; j < 4; ++j) gl2lds16(Ag + (size_t)(j * 8) * K + k0, Asl + j * 512);
#pragma unroll
        for (int j = 0; j < 4; ++j) gl2lds16(Bg + (size_t)(j * 8) * K + k0, Bsl + j * 512);
        __syncthreads();  // compiler drains vmcnt before barrier
#pragma unroll
        for (int kk = 0; kk < 2; ++kk) {
            bf16x8 af[4], bfr[4];
#pragma unroll
            for (int mi = 0; mi < 4; ++mi) {
                const int row = wr + mi * 16 + lr;
                const int idx = (row * 64 + kk * 32 + lg * 8) ^ ((row & 7) << 3);
                af[mi] = *(const bf16x8*)&As[idx];
            }
#pragma unroll
            for (int ni = 0; ni < 4; ++ni) {
                const int row = wc + ni * 16 + lr;
                const int idx = (row * 64 + kk * 32 + lg * 8) ^ ((row & 7) << 3);
                bfr[ni] = *(const bf16x8*)&Bs[idx];
            }
#pragma unroll
            for (int mi = 0; mi < 4; ++mi)
#pragma unroll
                for (int ni = 0; ni < 4; ++ni)
                    acc[mi][ni] = __builtin_amdgcn_mfma_f32_16x16x32_bf16(af[mi], bfr[ni],
                                                                          acc[mi][ni], 0, 0, 0);
        }
    }
#pragma unroll
    for (int mi = 0; mi < 4; ++mi)
#pragma unroll
        for (int ni = 0; ni < 4; ++ni) {
            const int row0 = bm + wr + mi * 16 + lg * 4;
            const int col = bn + wc + ni * 16 + lr;
#pragma unroll
            for (int r = 0; r < 4; ++r) {
                float v = acc[mi][ni][r];
                if (MODE == 2 && col >= FC_GATE) v = 1.f / (1.f + __expf(-v));
                if (MODE == 1)
                    ((float*)Cv)[(size_t)(row0 + r) * N + col] = v;
                else
                    ((u16*)Cv)[(size_t)(row0 + r) * N + col] = f2b(v);
            }
        }
}

// ---------------- merged up-projection GEMM (q-up + kv-up, one dispatch) ----------------
// blocks 0..767: q-tiles (24x32, own XCD swizzle cpx=96);
// blocks 768..1791: kv-tiles (32x32, own XCD swizzle cpx=128).
// Per-segment swizzle keeps L2 locality identical to standalone dispatches;
// merge only adds tail-overlap (kv blocks backfill q-up's partial last wave).
__global__ __launch_bounds__(256) void gemm_up_k(const u16* __restrict__ Aq,
                                                 const u16* __restrict__ Akv,
                                                 const u16* __restrict__ Btq,
                                                 const u16* __restrict__ Btkv,
                                                 u16* __restrict__ qbuf, u16* __restrict__ knope,
                                                 u16* __restrict__ vT) {
    __shared__ u16 As[128 * 64];
    __shared__ u16 Bs[128 * 64];
    const int t = threadIdx.x;
    const int bid = blockIdx.x;
    int tn, tm;
    bool isq;
    if (bid < 768) {  // q segment: identical mapping to standalone 24x32 dispatch
        isq = true;
        const int swz = (bid & 7) * 96 + (bid >> 3);
        tn = swz % 24;
        tm = swz / 24;
    } else {  // kv segment: identical mapping to standalone 32x32 dispatch
        isq = false;
        const int i = bid - 768;
        const int swz = (i & 7) * 128 + (i >> 3);
        tn = swz % 32;
        tm = swz / 32;
    }
    const int K = isq ? QLRANK : KVLRANK;
    const int bn = tn * 128, bm = tm * 128;
    const u16* A = isq ? Aq : Akv;
    const u16* Bt = isq ? Btq : Btkv;

    const int w = t >> 6, lane = t & 63;
    const int wr = (w >> 1) * 64, wc = (w & 1) * 64;
    const int lr = lane & 15, lg = lane >> 4;

    const int srow = w * 32 + (lane >> 3);
    const int scol = ((lane & 7) ^ ((lane >> 3) & 7)) * 8;
    const u16* Ag = A + (size_t)(bm + srow) * K + scol;
    const u16* Bg = Bt + (size_t)(bn + srow) * K + scol;
    u16* Asl = As + w * 2048;
    u16* Bsl = Bs + w * 2048;

    f32x4 acc[4][4];
#pragma unroll
    for (int i = 0; i < 4; ++i)
#pragma unroll
        for (int j = 0; j < 4; ++j) acc[i][j] = 0.f;

    for (int k0 = 0; k0 < K; k0 += 64) {
        __syncthreads();
#pragma unroll
        for (int j = 0; j < 4; ++j) gl2lds16(Ag + (size_t)(j * 8) * K + k0, Asl + j * 512);
#pragma unroll
        for (int j = 0; j < 4; ++j) gl2lds16(Bg + (size_t)(j * 8) * K + k0, Bsl + j * 512);
        __syncthreads();
#pragma unroll
        for (int kk = 0; kk < 2; ++kk) {
            bf16x8 af[4], bfr[4];
#pragma unroll
            for (int mi = 0; mi < 4; ++mi) {
                const int row = wr + mi * 16 + lr;
                const int idx = (row * 64 + kk * 32 + lg * 8) ^ ((row & 7) << 3);
                af[mi] = *(const bf16x8*)&As[idx];
            }
#pragma unroll
            for (int ni = 0; ni < 4; ++ni) {
                const int row = wc + ni * 16 + lr;
                const int idx = (row * 64 + kk * 32 + lg * 8) ^ ((row & 7) << 3);
                bfr[ni] = *(const bf16x8*)&Bs[idx];
            }
#pragma unroll
            for (int mi = 0; mi < 4; ++mi)
#pragma unroll
                for (int ni = 0; ni < 4; ++ni)
                    acc[mi][ni] = __builtin_amdgcn_mfma_f32_16x16x32_bf16(af[mi], bfr[ni],
                                                                          acc[mi][ni], 0, 0, 0);
        }
    }
#pragma unroll
    for (int mi = 0; mi < 4; ++mi)
#pragma unroll
        for (int ni = 0; ni < 4; ++ni) {
            const int row0 = bm + wr + mi * 16 + lg * 4;
            const int col = bn + wc + ni * 16 + lr;
            if (isq) {
#pragma unroll
                for (int r = 0; r < 4; ++r)
                    qbuf[(size_t)(row0 + r) * (NHEADS * QHEAD) + col] = f2b(acc[mi][ni][r]);
            } else {
                const int h = col >> 8, cd = col & 255;
                if (cd < 128) {
#pragma unroll
                    for (int r = 0; r < 4; ++r)
                        knope[(size_t)(row0 + r) * 2048 + h * 128 + cd] = f2b(acc[mi][ni][r]);
                } else {
                    u16x4 pk;
                    pk.x = f2b(acc[mi][ni][0]);
                    pk.y = f2b(acc[mi][ni][1]);
                    pk.z = f2b(acc[mi][ni][2]);
                    pk.w = f2b(acc[mi][ni][3]);
                    const int bb = row0 >> 11;
                    *(u16x4*)&vT[((size_t)((bb * 16 + h) * 128 + (cd - 128))) * SL +
                                 (row0 & (SL - 1))] = pk;
                }
            }
        }
}

// ---------------- fused RMS norms (q over fout cols [0,1536), kv over [1536,2048)) ----------------
__global__ __launch_bounds__(256) void rms2_k(const u16* __restrict__ fout,
                                              const float* __restrict__ qw,
                                              const float* __restrict__ kw, u16* __restrict__ qn,
                                              u16* __restrict__ kvn) {
    const int rid = blockIdx.x;
    const bool isq = rid < TTOK;
    const int row = isq ? rid : rid - TTOK;
    const int n = isq ? QLRANK : KVLRANK;
    const u16* x = fout + (size_t)row * FN + (isq ? 0 : FC_CKV);
    const float* w = isq ? qw : kw;
    u16* y = isq ? (qn + (size_t)row * QLRANK) : (kvn + (size_t)row * KVLRANK);
    const int t = threadIdx.x;
    float ss = 0.f;
    for (int d = t * 4; d < n; d += 1024) {
        const u16x4 u = *(const u16x4*)&x[d];
        const float a = b2f(u.x), b = b2f(u.y), c = b2f(u.z), e = b2f(u.w);
        ss += a * a + b * b + c * c + e * e;
    }
    ss += __shfl_down(ss, 32);
    ss += __shfl_down(ss, 16);
    ss += __shfl_down(ss, 8);
    ss += __shfl_down(ss, 4);
    ss += __shfl_down(ss, 2);
    ss += __shfl_down(ss, 1);
    __shared__ float red[5];
    if ((t & 63) == 0) red[t >> 6] = ss;
    __syncthreads();
    if (t == 0) red[4] = rsqrtf((red[0] + red[1] + red[2] + red[3]) / (float)n + 1e-6f);
    __syncthreads();
    const float sc = red[4];
    for (int d = t * 4; d < n; d += 1024) {
        const u16x4 u = *(const u16x4*)&x[d];
        const float4 wv = *(const float4*)&w[d];
        u16x4 o;
        o.x = f2b(b2f(u.x) * sc * (1.f + wv.x));
        o.y = f2b(b2f(u.y) * sc * (1.f + wv.y));
        o.z = f2b(b2f(u.z) * sc * (1.f + wv.z));
        o.w = f2b(b2f(u.w) * sc * (1.f + wv.w));
        *(u16x4*)&y[d] = o;
    }
}

// ---------------- RoPE (bf16): q in-place, fout rope slice -> kr ----------------
__global__ __launch_bounds__(64) void rope_k(u16* __restrict__ q, const u16* __restrict__ fout,
                                             u16* __restrict__ kr, const int* __restrict__ pos_ids) {
    const int tok = blockIdx.x * 2 + (threadIdx.x >> 5);
    const int j = threadIdx.x & 31;
    const int s = tok & (SL - 1);
    const float pos = (float)pos_ids[s];
    const float inv = 1.f / powf(10000.f, (float)(2 * j) / 64.f);
    const float f = pos * inv;
    const float c = cosf(f), sn = sinf(f);
    const u16* kc = fout + (size_t)tok * FN + FC_ROPE;
    const unsigned kp = *(const unsigned*)&kc[2 * j];
    const float ke = b2f((u16)(kp & 0xffff)), ko = b2f((u16)(kp >> 16));
    kr[tok * 64 + j] = f2b(ke * c - ko * sn);
    kr[tok * 64 + 32 + j] = f2b(ko * c + ke * sn);
#pragma unroll
    for (int h = 0; h < NHEADS; ++h) {
        u16* qb = q + (size_t)tok * (NHEADS * QHEAD) + h * QHEAD + DNOPE;
        const unsigned qp = *(const unsigned*)&qb[2 * j];
        const float qe = b2f((u16)(qp & 0xffff)), qo = b2f((u16)(qp >> 16));
        qb[j] = f2b(qe * c - qo * sn);
        qb[32 + j] = f2b(qo * c + qe * sn);
    }
}

// ---------------- MFMA flash attention, gate fused ----------------
// block = 256 (4 waves); q-tile 128 (32 rows/wave via 2 m-frags); key tiles of 64.
// grid (bh, qt): all q-tiles of one (b,h) share an XCD -> K/V L2 reuse by placement.
// reg-prefetch of next K/V tile hides L2 latency under compute.
// Q pre-scaled by scale*log2e; softmax in exp2 domain (v_exp_f32 direct).
// Row-sum l computed via MFMA-with-ones; defer-max gate via one 6-shuffle wave max.
#define PSTR 76
__global__ __launch_bounds__(256, 2) void mla_attn_k(const u16* __restrict__ qbuf,
                                                     const u16* __restrict__ knope,
                                                     const u16* __restrict__ kr,
                                                     const u16* __restrict__ vT,
                                                     const u16* __restrict__ gateb,
                                                     u16* __restrict__ outg) {
    __shared__ u16 Ks[64 * 200];
    __shared__ u16 Vt[128 * 72];
    __shared__ u16 Ps[4 * 32 * PSTR];
    const int bh = blockIdx.x;
    const int b = bh >> 4, h = bh & 15;
    const int q0 = blockIdx.y * 128;
    const int t = threadIdx.x, w = t >> 6, lane = t & 63;
    const int lr = lane & 15, lg = lane >> 4;
    const float qs = 0.07216878364870322f * 1.4426950408889634f;
    const float THR = 8.f * 1.4426950408889634f;

    int kRow[6], kC8[6];
#pragma unroll
    for (int c = 0; c < 6; ++c) {
        const int i = t + c * 256;
        kRow[c] = i / 24;
        kC8[c] = (i % 24) * 8;
    }
    int vRow[4], vC8[4];
#pragma unroll
    for (int c = 0; c < 4; ++c) {
        const int i = t + c * 256;
        vRow[c] = i >> 3;
        vC8[c] = (i & 7) * 8;
    }

    bf16x8 aq[2][6];
#pragma unroll
    for (int mi = 0; mi < 2; ++mi) {
        const int qrow = b * SL + q0 + w * 32 + mi * 16 + lr;
#pragma unroll
        for (int ks = 0; ks < 6; ++ks) {
            const u16x8 raw = *(const u16x8*)&qbuf[(size_t)qrow * (NHEADS * QHEAD) + h * QHEAD +
                                                   ks * 32 + lg * 8];
            bf16x8 o;
#pragma unroll
            for (int j = 0; j < 8; ++j) o[j] = (short)f2b(b2f(raw[j]) * qs);
            aq[mi][ks] = o;
        }
    }
    bf16x8 ones;
#pragma unroll
    for (int j = 0; j < 8; ++j) ones[j] = (short)0x3F80;

    f32x4 O[2][8];
#pragma unroll
    for (int mi = 0; mi < 2; ++mi)
#pragma unroll
        for (int df = 0; df < 8; ++df) O[mi][df] = 0.f;
    f32x4 Ol[2];
    Ol[0] = 0.f;
    Ol[1] = 0.f;
    float m[2][4];
#pragma unroll
    for (int mi = 0; mi < 2; ++mi)
#pragma unroll
        for (int r = 0; r < 4; ++r) m[mi][r] = -INFINITY;

    u16x8 kreg[6], vreg[4];
#define ATTN_ISSUE_K(K0)                                                                     \
    {                                                                                        \
        _Pragma("unroll") for (int c = 0; c < 6; ++c) {                                      \
            const int tok = b * SL + (K0) + kRow[c];                                         \
            kreg[c] = (kC8[c] < 128)                                                         \
                          ? *(const u16x8*)&knope[(size_t)tok * 2048 + h * 128 + kC8[c]]     \
                          : *(const u16x8*)&kr[(size_t)tok * 64 + (kC8[c] - 128)];           \
        }                                                                                    \
    }
#define ATTN_ISSUE_V(K0)                                                                     \
    {                                                                                        \
        _Pragma("unroll") for (int c = 0; c < 4; ++c)                                        \
            vreg[c] = *(const u16x8*)&vT[(size_t)(bh * 128 + vRow[c]) * SL + (K0) + vC8[c]]; \
    }

    ATTN_ISSUE_K(0);
    ATTN_ISSUE_V(0);

    for (int it = 0; it < SL / 64; ++it) {
        __syncthreads();
#pragma unroll
        for (int c = 0; c < 6; ++c) *(u16x8*)&Ks[kRow[c] * 200 + kC8[c]] = kreg[c];
#pragma unroll
        for (int c = 0; c < 4; ++c) *(u16x8*)&Vt[vRow[c] * 72 + vC8[c]] = vreg[c];
        __syncthreads();
        const bool more = (it + 1) < SL / 64;
        const int kn = (it + 1) * 64;
        if (more) ATTN_ISSUE_K(kn);

        f32x4 s[2][4];
#pragma unroll
        for (int mi = 0; mi < 2; ++mi)
#pragma unroll
            for (int nf = 0; nf < 4; ++nf) s[mi][nf] = 0.f;
#pragma unroll
        for (int ks = 0; ks < 6; ++ks) {
#pragma unroll
            for (int nf = 0; nf < 4; ++nf) {
                const bf16x8 bk = *(const bf16x8*)&Ks[(nf * 16 + lr) * 200 + ks * 32 + lg * 8];
                s[0][nf] = __builtin_amdgcn_mfma_f32_16x16x32_bf16(aq[0][ks], bk, s[0][nf], 0, 0, 0);
                s[1][nf] = __builtin_amdgcn_mfma_f32_16x16x32_bf16(aq[1][ks], bk, s[1][nf], 0, 0, 0);
            }
        }

        float g = -INFINITY;
#pragma unroll
        for (int mi = 0; mi < 2; ++mi)
#pragma unroll
            for (int r = 0; r < 4; ++r) {
                const float lmax =
                    fmaxf(fmaxf(s[mi][0][r], s[mi][1][r]), fmaxf(s[mi][2][r], s[mi][3][r]));
                g = fmaxf(g, lmax - m[mi][r]);
            }
        g = fmaxf(g, __shfl_xor(g, 1));
        g = fmaxf(g, __shfl_xor(g, 2));
        g = fmaxf(g, __shfl_xor(g, 4));
        g = fmaxf(g, __shfl_xor(g, 8));
        g = fmaxf(g, __shfl_xor(g, 16));
        g = fmaxf(g, __shfl_xor(g, 32));
        if (!(g <= THR)) {
#pragma unroll
            for (int mi = 0; mi < 2; ++mi)
#pragma unroll
                for (int r = 0; r < 4; ++r) {
                    float lm =
                        fmaxf(fmaxf(s[mi][0][r], s[mi][1][r]), fmaxf(s[mi][2][r], s[mi][3][r]));
                    lm = fmaxf(lm, __shfl_xor(lm, 1));
                    lm = fmaxf(lm, __shfl_xor(lm, 2));
                    lm = fmaxf(lm, __shfl_xor(lm, 4));
                    lm = fmaxf(lm, __shfl_xor(lm, 8));
                    const float mn = fmaxf(m[mi][r], lm);
                    const float al = fexp2(m[mi][r] - mn);
                    m[mi][r] = mn;
                    Ol[mi][r] *= al;
#pragma unroll
                    for (int df = 0; df < 8; ++df) O[mi][df][r] *= al;
                }
        }

#pragma unroll
        for (int mi = 0; mi < 2; ++mi) {
            const int pb = w * 32 * PSTR + mi * 16 * PSTR;
#pragma unroll
            for (int r = 0; r < 4; ++r) {
                const float mn = m[mi][r];
                const int prow = pb + (lg * 4 + r) * PSTR + lr;
                Ps[prow] = f2b(fexp2(s[mi][0][r] - mn));
                Ps[prow + 16] = f2b(fexp2(s[mi][1][r] - mn));
                Ps[prow + 32] = f2b(fexp2(s[mi][2][r] - mn));
                Ps[prow + 48] = f2b(fexp2(s[mi][3][r] - mn));
            }
        }

        if (more) ATTN_ISSUE_V(kn);

        bf16x8 pa[2][2];
#pragma unroll
        for (int mi = 0; mi < 2; ++mi)
#pragma unroll
            for (int ks2 = 0; ks2 < 2; ++ks2)
                pa[mi][ks2] =
                    *(const bf16x8*)&Ps[w * 32 * PSTR + (mi * 16 + lr) * PSTR + ks2 * 32 + lg * 8];
#pragma unroll
        for (int mi = 0; mi < 2; ++mi)
#pragma unroll
            for (int ks2 = 0; ks2 < 2; ++ks2)
                Ol[mi] = __builtin_amdgcn_mfma_f32_16x16x32_bf16(pa[mi][ks2], ones, Ol[mi], 0, 0, 0);
#pragma unroll
        for (int df = 0; df < 8; ++df)
#pragma unroll
            for (int ks2 = 0; ks2 < 2; ++ks2) {
                const bf16x8 bv = *(const bf16x8*)&Vt[(df * 16 + lr) * 72 + ks2 * 32 + lg * 8];
                O[0][df] = __builtin_amdgcn_mfma_f32_16x16x32_bf16(pa[0][ks2], bv, O[0][df], 0, 0, 0);
                O[1][df] = __builtin_amdgcn_mfma_f32_16x16x32_bf16(pa[1][ks2], bv, O[1][df], 0, 0, 0);
            }
    }
#pragma unroll
    for (int mi = 0; mi < 2; ++mi) {
        float invl[4];
#pragma unroll
        for (int r = 0; r < 4; ++r) invl[r] = 1.f / Ol[mi][r];
#pragma unroll
        for (int df = 0; df < 8; ++df)
#pragma unroll
            for (int r = 0; r < 4; ++r) {
                const int qq = b * SL + q0 + w * 32 + mi * 16 + lg * 4 + r;
                const int col = h * DVAL + df * 16 + lr;
                const float o = O[mi][df][r] * invl[r];
                const float gg = b2f(gateb[(size_t)qq * FN + col]);
                outg[(size_t)qq * (NHEADS * DVAL) + col] = f2b(o * gg);
            }
    }
}

extern "C" void kernel_launch(void* const* d_in, const int* in_sizes, int n_in, void* d_out,
                              int out_size, void* d_ws, size_t ws_size, hipStream_t stream) {
    const float* hs = (const float*)d_in[0];
    const int* pos = (const int*)d_in[1];
    const float* Wq_down = (const float*)d_in[2];
    const float* q_norm_w = (const float*)d_in[3];
    const float* Wq_up = (const float*)d_in[4];
    const float* Wkv_down = (const float*)d_in[5];
    const float* kv_norm_w = (const float*)d_in[6];
    const float* Wkv_up = (const float*)d_in[7];
    const float* W_gate = (const float*)d_in[8];
    const float* W_out = (const float*)d_in[9];
    float* out = (float*)d_out;

    u16* p = (u16*)d_ws;
    u16* hs16 = p;      p += (size_t)TTOK * HIDN;
    u16* wdown_t = p;   p += (size_t)FN * HIDN;
    u16* wqd_t = wdown_t;
    u16* wkvd_t = wdown_t + (size_t)QLRANK * HIDN;
    u16* wg_t = wdown_t + (size_t)FC_GATE * HIDN;
    u16* wqu_t = p;     p += (size_t)(NHEADS * QHEAD) * QLRANK;
    u16* wkvu_t = p;    p += (size_t)(NHEADS * 256) * KVLRANK;
    u16* wo_t = p;      p += (size_t)HIDN * (NHEADS * DVAL);
    u16* fout = p;      p += (size_t)TTOK * FN;
    u16* qdownN = p;    p += (size_t)TTOK * QLRANK;
    u16* qbuf = p;      p += (size_t)TTOK * (NHEADS * QHEAD);
    u16* kvn = p;       p += (size_t)TTOK * KVLRANK;
    u16* knope = p;     p += (size_t)TTOK * (NHEADS * DNOPE);
    u16* krb = p;       p += (size_t)TTOK * DROPE;
    u16* vTg = p;       p += (size_t)32 * 128 * SL;
    u16* outg = p;      p += (size_t)TTOK * (NHEADS * DVAL);

    const dim3 blk(256);

    precast_k<<<dim3(6816), blk, 0, stream>>>(Wq_down, Wq_up, Wkv_down, Wkv_up, W_gate, W_out, hs,
                                              wqd_t, wqu_t, wkvd_t, wkvu_t, wg_t, wo_t, hs16);

    gemm_bf16_k<2><<<dim3(FN / 128, TTOK / 128), blk, 0, stream>>>(hs16, wdown_t, fout, TTOK, FN,
                                                                   HIDN);
    rms2_k<<<dim3(2 * TTOK), blk, 0, stream>>>(fout, q_norm_w, kv_norm_w, qdownN, kvn);
    // merged q-up + kv-up with per-segment XCD swizzle (locality == standalone dispatches)
    gemm_up_k<<<dim3(1792), blk, 0, stream>>>(qdownN, kvn, wqu_t, wkvu_t, qbuf, knope, vTg);
    rope_k<<<dim3(TTOK / 2), dim3(64), 0, stream>>>(qbuf, fout, krb, pos);

    mla_attn_k<<<dim3(32, SL / 128), blk, 0, stream>>>(qbuf, knope, krb, vTg, fout + FC_GATE, outg);

    gemm_bf16_k<1><<<dim3(HIDN / 128, TTOK / 128), blk, 0, stream>>>(outg, wo_t, out, TTOK, HIDN,
                                                                     NHEADS * DVAL);
}